// Round 9
// baseline (17.537 us; speedup 1.0000x reference)
//
#include <hip/hip_runtime.h>

// predictions: [B=64, T=8192, D=64] f32 ; start_timestamp: int32 scalar (device)
// loss = sum_{b, j in [s,s+L), d} (p[b,j+1,d]-p[b,j,d])^2 / B - 0.5
// L = 4096, INHERENT_NEIGHBORHOOD = 0.5

#define BATCH 64
#define TDIM  8192
#define DDIM  64
#define LWIN  4096

#define D4    16                     // float4 per row
#define TD4   (TDIM * D4)            // 131072 float4 per-batch full span

#define RCHAIN   16                  // rows per chain: 17 loads -> 16 diffs (1.0625x amp)
#define NTHREADS 256
#define NCHAINS  (LWIN / RCHAIN)     // 256 chains per (b, column)
#define TOTTHR   (BATCH * D4 * NCHAINS)   // 262144 threads, 1 chain each
#define NBLOCKS  (TOTTHR / NTHREADS)      // 1024
#define NWAVES   (TOTTHR / 64)            // 4096

// Fence-free hierarchical termination, now PER-WAVE (no LDS, no syncthreads):
// each u64 packs bits[63:52]=count, bits[51:0]=fixed-point (2^-20) sum; one
// atomicAdd carries both (memory-side atomics are device-coherent; integer
// adds commute -> bit-deterministic). 64 padded sub-counters x 64 waves each;
// sub-last waves fold into nl_fin; the unique global-last wave writes out.
// All counters load as 0 and self-restore to 0 every call.
#define NSUB      64
#define SUBPAD    8                   // 64B line padding between sub-counters
#define PER_SUB   (NWAVES / NSUB)     // 64 waves per sub-counter
#define CNT_SHIFT 52
#define SUM_MASK  ((1ULL << CNT_SHIFT) - 1ULL)
#define FIX_SCALE 1048576.0           // 2^20

__device__ unsigned long long nl_sub[NSUB * SUBPAD] = {0};
__device__ unsigned long long nl_fin = 0ULL;

__global__ __launch_bounds__(NTHREADS) void nl_fused_kernel(
    const float4* __restrict__ pred, const int* __restrict__ s_ptr,
    float* __restrict__ out) {
    const int s   = *s_ptr;
    const int tid = blockIdx.x * NTHREADS + threadIdx.x;
    const int c    = tid & 15;             // float4 column within row
    const int g    = tid >> 4;             // chain id
    const int jblk = g & (NCHAINS - 1);    // row-block within window
    const int b    = g >> 8;               // batch   (NCHAINS = 256 = 2^8)

    const float4* p = pred + ((size_t)b * TD4 + (size_t)(s + jblk * RCHAIN) * D4 + c);

    // 17 consecutive rows, rolling pair (R8 lesson: TLP covers latency;
    // per-thread load scheduling is irrelevant -> keep VGPR low instead).
    float4 prev = p[0];
    float acc = 0.0f;
    #pragma unroll
    for (int i = 1; i <= RCHAIN; ++i) {
        const float4 cur = p[i * D4];
        const float dx = cur.x - prev.x;
        const float dy = cur.y - prev.y;
        const float dz = cur.z - prev.z;
        const float dw = cur.w - prev.w;
        acc += dx * dx + dy * dy + dz * dz + dw * dw;
        prev = cur;
    }

    // wave64 reduce (only cross-thread step in the whole kernel)
    #pragma unroll
    for (int off = 32; off > 0; off >>= 1) acc += __shfl_down(acc, off, 64);

    if ((threadIdx.x & 63) == 0) {
        const int wgid = (blockIdx.x << 2) | (threadIdx.x >> 6);  // global wave id
        const int sub  = (wgid & (NSUB - 1)) * SUBPAD;
        const unsigned long long contrib =
            (1ULL << CNT_SHIFT) | (unsigned long long)((double)acc * FIX_SCALE);
        const unsigned long long oldv = atomicAdd(&nl_sub[sub], contrib);
        const unsigned long long newv = oldv + contrib;
        if ((newv >> CNT_SHIFT) == (unsigned long long)PER_SUB) {
            atomicExch(&nl_sub[sub], 0ULL);           // restore for next call
            const unsigned long long c2 =
                (1ULL << CNT_SHIFT) | (newv & SUM_MASK);
            const unsigned long long old2 = atomicAdd(&nl_fin, c2);
            const unsigned long long new2 = old2 + c2;
            if ((new2 >> CNT_SHIFT) == (unsigned long long)NSUB) {
                const double total = (double)(new2 & SUM_MASK) * (1.0 / FIX_SCALE);
                out[0] = (float)(total * (1.0 / BATCH) - 0.5);  // INHERENT_NEIGHBORHOOD
                atomicExch(&nl_fin, 0ULL);            // restore for next call
            }
        }
    }
}

extern "C" void kernel_launch(void* const* d_in, const int* in_sizes, int n_in,
                              void* d_out, int out_size, void* d_ws, size_t ws_size,
                              hipStream_t stream) {
    const float4* pred = (const float4*)d_in[0];
    const int* s_ptr   = (const int*)d_in[1];
    float* out         = (float*)d_out;

    nl_fused_kernel<<<NBLOCKS, NTHREADS, 0, stream>>>(pred, s_ptr, out);
}

// Round 10
// 17.460 us; speedup vs baseline: 1.0044x; 1.0044x over previous
//
#include <hip/hip_runtime.h>

// predictions: [B=64, T=8192, D=64] f32 ; start_timestamp: int32 scalar (device)
// loss = sum_{b, j in [s,s+L), d} (p[b,j+1,d]-p[b,j,d])^2 / B - 0.5
// L = 4096, INHERENT_NEIGHBORHOOD = 0.5

#define BATCH 64
#define TDIM  8192
#define DDIM  64
#define LWIN  4096

#define D4    16                     // float4 per row
#define TD4   (TDIM * D4)            // 131072 float4 per-batch full span

#define RCHAIN   8                   // rows per chain: 9 loads -> 8 diffs
#define NTHREADS 256
#define NCHAINS  (LWIN / RCHAIN)     // 512 chains per (b, column)
#define TOTTHR   (BATCH * D4 * NCHAINS)   // 524288 threads, 1 chain each
#define NBLOCKS  (TOTTHR / NTHREADS)      // 2048  (8192 waves = 32/CU, max occ)
#define NWAVES   (TOTTHR / 64)            // 8192

#define NXCD 8

// Fence-free hierarchical termination, per-wave (no LDS / no syncthreads):
// u64 packs bits[63:52]=count, bits[51:0]=fixed-point(2^-20) sum; one
// atomicAdd carries both; integer adds commute -> bit-deterministic.
// 128 padded sub-counters x 64 waves each; sub-last folds into nl_fin;
// global-last writes out. All counters self-restore to 0 every call.
#define NSUB      128
#define SUBPAD    8                   // 64B line padding
#define PER_SUB   (NWAVES / NSUB)     // 64 waves per sub-counter
#define CNT_SHIFT 52
#define SUM_MASK  ((1ULL << CNT_SHIFT) - 1ULL)
#define FIX_SCALE 1048576.0           // 2^20

__device__ unsigned long long nl_sub[NSUB * SUBPAD] = {0};
__device__ unsigned long long nl_fin = 0ULL;

__global__ __launch_bounds__(NTHREADS) void nl_fused_kernel(
    const float4* __restrict__ pred, const int* __restrict__ s_ptr,
    float* __restrict__ out) {
    const int s = *s_ptr;

    // Bijective XCD swizzle (nwg=2048, 2048%8==0): each XCD gets a contiguous
    // 256-block slab -> contiguous ~8.4MB memory range per XCD L2.
    const int bid  = (int)blockIdx.x;
    const int swz  = (bid & (NXCD - 1)) * (NBLOCKS / NXCD) + (bid >> 3);

    const int tid = swz * NTHREADS + threadIdx.x;
    const int c    = tid & 15;             // float4 column within row
    const int g    = tid >> 4;             // chain id
    const int jblk = g & (NCHAINS - 1);    // row-block within window
    const int b    = g >> 9;               // batch   (NCHAINS = 512 = 2^9)

    const float4* p = pred + ((size_t)b * TD4 + (size_t)(s + jblk * RCHAIN) * D4 + c);

    // 9 consecutive rows at column c; rolling pair keeps VGPR low (R8 lesson:
    // TLP covers latency, per-thread load scheduling is irrelevant).
    float4 prev = p[0];
    float acc = 0.0f;
    #pragma unroll
    for (int i = 1; i <= RCHAIN; ++i) {
        const float4 cur = p[i * D4];
        const float dx = cur.x - prev.x;
        const float dy = cur.y - prev.y;
        const float dz = cur.z - prev.z;
        const float dw = cur.w - prev.w;
        acc += dx * dx + dy * dy + dz * dz + dw * dw;
        prev = cur;
    }

    // wave64 reduce (only cross-thread step in the kernel)
    #pragma unroll
    for (int off = 32; off > 0; off >>= 1) acc += __shfl_down(acc, off, 64);

    if ((threadIdx.x & 63) == 0) {
        const int wgid = (bid << 2) | (threadIdx.x >> 6);   // launch-order wave id
        const int sub  = (wgid & (NSUB - 1)) * SUBPAD;
        const unsigned long long contrib =
            (1ULL << CNT_SHIFT) | (unsigned long long)((double)acc * FIX_SCALE);
        const unsigned long long oldv = atomicAdd(&nl_sub[sub], contrib);
        const unsigned long long newv = oldv + contrib;
        if ((newv >> CNT_SHIFT) == (unsigned long long)PER_SUB) {
            atomicExch(&nl_sub[sub], 0ULL);           // restore for next call
            const unsigned long long c2 =
                (1ULL << CNT_SHIFT) | (newv & SUM_MASK);
            const unsigned long long old2 = atomicAdd(&nl_fin, c2);
            const unsigned long long new2 = old2 + c2;
            if ((new2 >> CNT_SHIFT) == (unsigned long long)NSUB) {
                const double total = (double)(new2 & SUM_MASK) * (1.0 / FIX_SCALE);
                out[0] = (float)(total * (1.0 / BATCH) - 0.5);  // INHERENT_NEIGHBORHOOD
                atomicExch(&nl_fin, 0ULL);            // restore for next call
            }
        }
    }
}

extern "C" void kernel_launch(void* const* d_in, const int* in_sizes, int n_in,
                              void* d_out, int out_size, void* d_ws, size_t ws_size,
                              hipStream_t stream) {
    const float4* pred = (const float4*)d_in[0];
    const int* s_ptr   = (const int*)d_in[1];
    float* out         = (float*)d_out;

    nl_fused_kernel<<<NBLOCKS, NTHREADS, 0, stream>>>(pred, s_ptr, out);
}